// Round 3
// baseline (21462.567 us; speedup 1.0000x reference)
//
#include <hip/hip_runtime.h>
#include <hip/hip_bf16.h>

#define PX 9216      // 96*96
#define LL 9216
#define HALF_L 4608
#define CCH 32       // emitted steps per chunk
#define NCHUNK 288   // 9216/32
#define WARM_BF 128
#define WARM_F32 512
#define NITER 50
#define CB 4         // conv batch chunk

// ws offsets (floats)
#define OFF_WC   0        // 32 scaled GRU consts
#define OFF_FLAG 32
#define OFF_HL   40       // 128
#define OFF_W1   192      // 144
#define OFF_B1   336      // 16
#define OFF_W2   384      // 4608
#define OFF_B2   4992     // 32
#define OFF_W3   5024     // 864
#define OFF_B3   5888     // 3
#define OFF_KX   5896     // 9
#define OFF_KY   5908     // 9
#define OFF_GRAY 8192     // 294912
#define OFF_G    303104   // 294912
#define OFF_MK   598016   // 294912
#define OFF_A4A  892928   // 294912 pos * float4 = 1179648
#define OFF_A4B  2072640  // 1179648
#define OFF_A2A  3252352  // 294912 pos * float2 = 589824
#define OFF_A2B  3842240  // 589824
#define OFF_Y    4432128  // 589824 ; end 5021952 floats = 20.1 MB
// conv scratch aliased over regions dead until GRU iter >= 1:
#define OFF_C1   OFF_A4B            // CB*16*9216 = 589824 <= 1179648
#define OFF_C2   OFF_A2B            // CB*32*9216 = 1179648 spans A2B+Y exactly

static __device__ __forceinline__ float ldv(const void* p, long i, bool isb) {
    return isb ? __bfloat162float(((const __hip_bfloat16*)p)[i])
               : ((const float*)p)[i];
}

__global__ __launch_bounds__(256) void k_prep(
    float* __restrict__ ws, const void* img,
    const void* w1, const void* b1, const void* w2, const void* b2,
    const void* w3, const void* b3, const void* kx, const void* ky,
    const void* wih, const void* whh, const void* bih, const void* bhh)
{
    __shared__ float s_isb;
    int t = threadIdx.x;
    if (t == 0) {
        const unsigned short* u16 = (const unsigned short*)img;
        int cnt = 0;
        for (int k = 0; k < 256; ++k) {
            unsigned short u = u16[k];
            int e = (u >> 7) & 0xFF;
            bool ok = (u == 0) || (((u & 0x8000) == 0) && e >= 0x20 && e <= 0x7E);
            cnt += ok ? 1 : 0;
        }
        s_isb = (cnt >= 224) ? 1.f : 0.f;
        ws[OFF_FLAG] = s_isb;
    }
    __syncthreads();
    bool isb = s_isb > 0.5f;

    for (int i = t; i < 144; i += 256) { int co = i/9, tap = i%9; ws[OFF_W1 + tap*16 + co] = ldv(w1,i,isb); }
    for (int i = t; i < 16; i += 256) ws[OFF_B1+i] = ldv(b1,i,isb);
    for (int i = t; i < 4608; i += 256) { int co = i/144, r = i%144, ci = r/9, tap = r%9;
        ws[OFF_W2 + (ci*9+tap)*32 + co] = ldv(w2,i,isb); }
    for (int i = t; i < 32; i += 256) ws[OFF_B2+i] = ldv(b2,i,isb);
    for (int i = t; i < 864; i += 256) { int o = i/288, r = i%288, ci = r/9, tap = r%9;
        ws[OFF_W3 + (ci*9+tap)*3 + o] = ldv(w3,i,isb); }
    for (int i = t; i < 3; i += 256) ws[OFF_B3+i] = ldv(b3,i,isb);
    for (int i = t; i < 9; i += 256) { ws[OFF_KX+i] = ldv(kx,i,isb); ws[OFF_KY+i] = ldv(ky,i,isb); }
    for (int i = t; i < 128; i += 256) ws[OFF_HL+i] = 0.f;
    if (t == 0) {
        const float C1 = 1.4426950408889634f;
        for (int g = 0; g < 4; ++g) {   // r,z gates: scale by -log2e
            ws[OFF_WC + g*2+0]     = -C1*ldv(wih, g*2+0, isb);
            ws[OFF_WC + g*2+1]     = -C1*ldv(wih, g*2+1, isb);
            ws[OFF_WC + 8 + g*2+0] = -C1*ldv(whh, g*2+0, isb);
            ws[OFF_WC + 8 + g*2+1] = -C1*ldv(whh, g*2+1, isb);
            ws[OFF_WC + 16 + g]    = -C1*(ldv(bih,g,isb)+ldv(bhh,g,isb));
        }
        for (int j = 0; j < 2; ++j) {   // n gate: tanh(t)=1-2/(1+2^(2*log2e*t))
            int g = 4+j;
            ws[OFF_WC + 20 + j*2+0] = 2.f*C1*ldv(wih, g*2+0, isb);
            ws[OFF_WC + 20 + j*2+1] = 2.f*C1*ldv(wih, g*2+1, isb);
            ws[OFF_WC + 24 + j*2+0] = 2.f*C1*ldv(whh, g*2+0, isb);
            ws[OFF_WC + 24 + j*2+1] = 2.f*C1*ldv(whh, g*2+1, isb);
            ws[OFF_WC + 28 + j]     = 2.f*C1*ldv(bih, g, isb);
            ws[OFF_WC + 30 + j]     = 2.f*C1*ldv(bhh, g, isb);
        }
    }
}

__global__ __launch_bounds__(256) void k_gray(const void* __restrict__ img,
                                              float* __restrict__ ws)
{
    bool isb = ws[OFF_FLAG] > 0.5f;
    int t = blockIdx.x*256 + threadIdx.x;
    int b = t / PX, p = t - b*PX;
    long base = (long)b*3*PX;
    float r  = ldv(img, base + p, isb);
    float g  = ldv(img, base + PX + p, isb);
    float bl = ldv(img, base + 2*PX + p, isb);
    ws[OFF_GRAY + t] = fmaf(0.2989f, r, fmaf(0.587f, g, 0.114f*bl));
}

__global__ __launch_bounds__(256) void k_sobel(float* __restrict__ ws)
{
    int t = blockIdx.x*256 + threadIdx.x;
    int b = t / PX, p = t - b*PX;
    int y = p / 96, x = p - y*96;
    const float* g = ws + OFF_GRAY + b*PX;
    float gx = 0.f, gy = 0.f;
    #pragma unroll
    for (int dy = 0; dy < 3; ++dy)
    #pragma unroll
    for (int dx = 0; dx < 3; ++dx) {
        int yy = y+dy-1, xx = x+dx-1;
        float v = (yy >= 0 && yy < 96 && xx >= 0 && xx < 96) ? g[yy*96+xx] : 0.f;
        gx = fmaf(v, ws[OFF_KX + dy*3+dx], gx);
        gy = fmaf(v, ws[OFF_KY + dy*3+dx], gy);
    }
    ws[OFF_G + t] = sqrtf(fmaf(gx, gx, gy*gy));
}

__global__ __launch_bounds__(256) void k_conv1(float* __restrict__ ws, int b0)
{
    int t = blockIdx.x*256 + threadIdx.x;   // CB*9216 threads
    int bb = t / PX, p = t - bb*PX;
    int y = p / 96, x = p - y*96;
    const float* g = ws + OFF_GRAY + (b0+bb)*PX;
    float acc[16];
    #pragma unroll
    for (int co = 0; co < 16; ++co) acc[co] = 0.f;
    #pragma unroll
    for (int dy = 0; dy < 3; ++dy)
    #pragma unroll
    for (int dx = 0; dx < 3; ++dx) {
        int yy = y+dy-1, xx = x+dx-1;
        float v = (yy >= 0 && yy < 96 && xx >= 0 && xx < 96) ? g[yy*96+xx] : 0.f;
        const float* w = ws + OFF_W1 + (dy*3+dx)*16;
        #pragma unroll
        for (int co = 0; co < 16; ++co) acc[co] = fmaf(v, w[co], acc[co]);
    }
    float* o = ws + OFF_C1 + bb*16*PX + p;
    #pragma unroll
    for (int co = 0; co < 16; ++co)
        o[co*PX] = fmaxf(acc[co] + ws[OFF_B1+co], 0.f);
}

__global__ __launch_bounds__(256) void k_conv2(float* __restrict__ ws)
{
    __shared__ float tile[16*324];   // 16 ci x 18x18 halo
    int bb = blockIdx.x / 36;
    int tI = blockIdx.x % 36;
    int ty0 = (tI / 6) * 16, tx0 = (tI % 6) * 16;
    int t = threadIdx.x;
    for (int i = t; i < 5184; i += 256) {
        int ci = i / 324, r = i - ci*324;
        int yy = r / 18, xx = r - yy*18;
        int gy = ty0 + yy - 1, gx = tx0 + xx - 1;
        float v = 0.f;
        if (gy >= 0 && gy < 96 && gx >= 0 && gx < 96)
            v = ws[OFF_C1 + (bb*16 + ci)*PX + gy*96 + gx];
        tile[i] = v;
    }
    __syncthreads();
    int ty = t / 16, tx = t - (t/16)*16;
    float acc[32];
    #pragma unroll
    for (int co = 0; co < 32; ++co) acc[co] = 0.f;
    for (int ci = 0; ci < 16; ++ci) {
        #pragma unroll
        for (int dy = 0; dy < 3; ++dy)
        #pragma unroll
        for (int dx = 0; dx < 3; ++dx) {
            float v = tile[ci*324 + (ty+dy)*18 + (tx+dx)];
            const float* w = ws + OFF_W2 + (ci*9 + dy*3 + dx)*32;
            #pragma unroll
            for (int co = 0; co < 32; ++co) acc[co] = fmaf(v, w[co], acc[co]);
        }
    }
    int p = (ty0+ty)*96 + tx0 + tx;
    float* o = ws + OFF_C2 + bb*32*PX + p;
    #pragma unroll
    for (int co = 0; co < 32; ++co)
        o[co*PX] = fmaxf(acc[co] + ws[OFF_B2+co], 0.f);
}

__global__ __launch_bounds__(256) void k_conv3(float* __restrict__ ws, int b0)
{
    int t = blockIdx.x*256 + threadIdx.x;
    int bb = t / PX, p = t - bb*PX;
    int y = p / 96, x = p - y*96;
    float a0 = 0.f, a1 = 0.f, a2 = 0.f;
    for (int ci = 0; ci < 32; ++ci) {
        const float* s = ws + OFF_C2 + (bb*32 + ci)*PX;
        #pragma unroll
        for (int dy = 0; dy < 3; ++dy)
        #pragma unroll
        for (int dx = 0; dx < 3; ++dx) {
            int yy = y+dy-1, xx = x+dx-1;
            float v = (yy >= 0 && yy < 96 && xx >= 0 && xx < 96) ? s[yy*96+xx] : 0.f;
            const float* w = ws + OFF_W3 + (ci*9 + dy*3 + dx)*3;
            a0 = fmaf(v, w[0], a0);
            a1 = fmaf(v, w[1], a1);
            a2 = fmaf(v, w[2], a2);
        }
    }
    a0 += ws[OFF_B3+0]; a1 += ws[OFF_B3+1]; a2 += ws[OFF_B3+2];
    int m = 0; float best = a0;
    if (a1 > best) { best = a1; m = 1; }
    if (a2 > best) { m = 2; }
    ws[OFF_MK + (b0+bb)*PX + p] = (float)m;
}

// pack x=(v0,v1) per position and seed gi buffers for GRU iteration 0
__global__ __launch_bounds__(256) void k_pack(float* __restrict__ ws)
{
    int t = blockIdx.x*256 + threadIdx.x;   // 0..294911
    int b = t / LL, l = t - b*LL;
    float v0, v1;
    if (l < HALF_L) {
        const float* m = ws + OFF_MK + b*PX + 2*l;
        v0 = m[0]; v1 = m[1];
    } else {
        const float* g = ws + OFF_G + b*PX + 2*(l - HALF_L);
        v0 = g[0]; v1 = g[1];
    }
    const float* kk = ws + OFF_WC;
    float4 g4;
    g4.x = fmaf(kk[0], v0, fmaf(kk[1], v1, kk[16]));
    g4.y = fmaf(kk[2], v0, fmaf(kk[3], v1, kk[17]));
    g4.z = fmaf(kk[4], v0, fmaf(kk[5], v1, kk[18]));
    g4.w = fmaf(kk[6], v0, fmaf(kk[7], v1, kk[19]));
    float2 g2;
    g2.x = fmaf(kk[20], v0, fmaf(kk[21], v1, kk[28]));
    g2.y = fmaf(kk[22], v0, fmaf(kk[23], v1, kk[29]));
    ((float4*)(ws + OFF_A4A))[t] = g4;
    ((float2*)(ws + OFF_A2A))[t] = g2;
}

__global__ __launch_bounds__(1024) void k_gru(const float* __restrict__ ws,
                                              const float4* __restrict__ g4in,
                                              const float2* __restrict__ g2in,
                                              float4* __restrict__ g4out,
                                              float2* __restrict__ g2out,
                                              float2* __restrict__ yout,
                                              const float* __restrict__ hlin,
                                              float* __restrict__ hlout)
{
    int i = blockIdx.x*1024 + threadIdx.x;  // 9216 threads exactly
    int b = i / NCHUNK, c = i - b*NCHUNK;
    int warm = (ws[OFF_FLAG] > 0.5f) ? WARM_BF : WARM_F32;
    float kk[32];
    #pragma unroll
    for (int j = 0; j < 32; ++j) kk[j] = ws[OFF_WC + j];

    int emit = c * CCH;
    int end  = emit + CCH;
    int start = emit - warm;
    float h0, h1;
    if (start <= 0) { start = 0; h0 = hlin[2*b]; h1 = hlin[2*b+1]; }
    else            { h0 = 0.f; h1 = 0.f; }

    const float4* s4 = g4in + b*LL;
    const float2* s2 = g2in + b*LL;
    float4*       d4 = g4out + b*LL;
    float2*       d2 = g2out + b*LL;
    float2*       dy = yout  + b*LL;

    auto STEP = [&](const float4& g4, float gn0, float gn1) {
        float ar0 = fmaf(kk[8],  h0, fmaf(kk[9],  h1, g4.x));
        float ar1 = fmaf(kk[10], h0, fmaf(kk[11], h1, g4.y));
        float az0 = fmaf(kk[12], h0, fmaf(kk[13], h1, g4.z));
        float az1 = fmaf(kk[14], h0, fmaf(kk[15], h1, g4.w));
        float er0 = __builtin_amdgcn_exp2f(fminf(ar0, 60.f));
        float er1 = __builtin_amdgcn_exp2f(fminf(ar1, 60.f));
        float ez0 = __builtin_amdgcn_exp2f(fminf(az0, 60.f));
        float ez1 = __builtin_amdgcn_exp2f(fminf(az1, 60.f));
        float tr0 = 1.f + er0, tr1 = 1.f + er1;
        float tz0 = 1.f + ez0, tz1 = 1.f + ez1;
        float iR = __builtin_amdgcn_rcpf(tr0*tr1);
        float iZ = __builtin_amdgcn_rcpf(tz0*tz1);
        float r0 = iR*tr1, r1 = iR*tr0;
        float z0 = iZ*tz1, z1 = iZ*tz0;
        float hn0 = fmaf(kk[24], h0, fmaf(kk[25], h1, kk[30]));
        float hn1 = fmaf(kk[26], h0, fmaf(kk[27], h1, kk[31]));
        float u0 = fmaf(r0, hn0, gn0);
        float u1 = fmaf(r1, hn1, gn1);
        float e0 = __builtin_amdgcn_exp2f(fminf(u0, 60.f));
        float e1 = __builtin_amdgcn_exp2f(fminf(u1, 60.f));
        float s0 = 1.f + e0, s1 = 1.f + e1;
        float iN = __builtin_amdgcn_rcpf(s0*s1);
        float m2 = -2.f*iN;
        float n0 = fmaf(m2, s1, 1.f);
        float n1 = fmaf(m2, s0, 1.f);
        h0 = fmaf(z0, h0 - n0, n0);
        h1 = fmaf(z1, h1 - n1, n1);
    };

    auto GI4 = [&](float y0, float y1) {
        return make_float4(fmaf(kk[0], y0, fmaf(kk[1], y1, kk[16])),
                           fmaf(kk[2], y0, fmaf(kk[3], y1, kk[17])),
                           fmaf(kk[4], y0, fmaf(kk[5], y1, kk[18])),
                           fmaf(kk[6], y0, fmaf(kk[7], y1, kk[19])));
    };

    // current-trip registers
    float4 c40 = s4[start], c41 = s4[start+1], c42 = s4[start+2], c43 = s4[start+3];
    float4 c2a = *(const float4*)(s2 + start);       // gn for pos l, l+1
    float4 c2b = *(const float4*)(s2 + start + 2);   // gn for pos l+2, l+3

    for (int l = start; l < end; l += 4) {
        float4 n40 = s4[l+4], n41 = s4[l+5], n42 = s4[l+6], n43 = s4[l+7];
        float4 n2a = *(const float4*)(s2 + l + 4);
        float4 n2b = *(const float4*)(s2 + l + 6);
        STEP(c40, c2a.x, c2a.y); float y00 = fmaxf(h0,0.f), y01 = fmaxf(h1,0.f);
        STEP(c41, c2a.z, c2a.w); float y10 = fmaxf(h0,0.f), y11 = fmaxf(h1,0.f);
        STEP(c42, c2b.x, c2b.y); float y20 = fmaxf(h0,0.f), y21 = fmaxf(h1,0.f);
        STEP(c43, c2b.z, c2b.w); float y30 = fmaxf(h0,0.f), y31 = fmaxf(h1,0.f);
        if (l >= emit) {
            d4[l]   = GI4(y00, y01);
            d4[l+1] = GI4(y10, y11);
            d4[l+2] = GI4(y20, y21);
            d4[l+3] = GI4(y30, y31);
            *(float4*)(d2 + l)     = make_float4(
                fmaf(kk[20],y00, fmaf(kk[21],y01, kk[28])),
                fmaf(kk[22],y00, fmaf(kk[23],y01, kk[29])),
                fmaf(kk[20],y10, fmaf(kk[21],y11, kk[28])),
                fmaf(kk[22],y10, fmaf(kk[23],y11, kk[29])));
            *(float4*)(d2 + l + 2) = make_float4(
                fmaf(kk[20],y20, fmaf(kk[21],y21, kk[28])),
                fmaf(kk[22],y20, fmaf(kk[23],y21, kk[29])),
                fmaf(kk[20],y30, fmaf(kk[21],y31, kk[28])),
                fmaf(kk[22],y30, fmaf(kk[23],y31, kk[29])));
            *(float4*)(dy + l)     = make_float4(y00, y01, y10, y11);
            *(float4*)(dy + l + 2) = make_float4(y20, y21, y30, y31);
        }
        c40 = n40; c41 = n41; c42 = n42; c43 = n43;
        c2a = n2a; c2b = n2b;
    }
    if (c == NCHUNK-1) { hlout[2*b] = h0; hlout[2*b+1] = h1; }
}

__global__ __launch_bounds__(256) void k_out(const float* __restrict__ ws,
                                             const void* __restrict__ ow,
                                             const void* __restrict__ ob,
                                             void* __restrict__ out)
{
    bool isb = ws[OFF_FLAG] > 0.5f;
    int t = blockIdx.x*256 + threadIdx.x;
    int b = t / PX, p = t - b*PX;
    float2 v = ((const float2*)(ws + OFF_Y))[b*LL + p];
    #pragma unroll
    for (int o = 0; o < 3; ++o) {
        float w0 = ldv(ow, o*2,   isb);
        float w1 = ldv(ow, o*2+1, isb);
        float bi = ldv(ob, o,     isb);
        float r = fmaf(v.y, w1, fmaf(v.x, w0, bi));
        long idx = (long)(b*3 + o)*PX + p;
        if (isb) ((__hip_bfloat16*)out)[idx] = __float2bfloat16(r);
        else     ((float*)out)[idx] = r;
    }
}

extern "C" void kernel_launch(void* const* d_in, const int* in_sizes, int n_in,
                              void* d_out, int out_size, void* d_ws, size_t ws_size,
                              hipStream_t stream)
{
    (void)in_sizes; (void)n_in; (void)out_size; (void)ws_size;
    float* ws = (float*)d_ws;
    const void* img = d_in[0];
    const void* kx  = d_in[1];
    const void* ky  = d_in[2];
    const void* w1  = d_in[3];
    const void* b1  = d_in[4];
    const void* w2  = d_in[5];
    const void* b2  = d_in[6];
    const void* w3  = d_in[7];
    const void* b3  = d_in[8];
    const void* wih = d_in[9];
    const void* whh = d_in[10];
    const void* bih = d_in[11];
    const void* bhh = d_in[12];
    const void* owp = d_in[13];
    const void* obp = d_in[14];

    k_prep<<<1, 256, 0, stream>>>(ws, img, w1,b1,w2,b2,w3,b3,kx,ky,wih,whh,bih,bhh);
    k_gray<<<1152, 256, 0, stream>>>(img, ws);
    k_sobel<<<1152, 256, 0, stream>>>(ws);
    for (int q = 0; q < 8; ++q) {          // batch chunks of CB=4
        k_conv1<<<144, 256, 0, stream>>>(ws, q*CB);
        k_conv2<<<144, 256, 0, stream>>>(ws);
        k_conv3<<<144, 256, 0, stream>>>(ws, q*CB);
    }
    k_pack<<<1152, 256, 0, stream>>>(ws);

    float4* a4a = (float4*)(ws + OFF_A4A);
    float4* a4b = (float4*)(ws + OFF_A4B);
    float2* a2a = (float2*)(ws + OFF_A2A);
    float2* a2b = (float2*)(ws + OFF_A2B);
    float2* y   = (float2*)(ws + OFF_Y);
    float* hl = ws + OFF_HL;
    for (int it = 0; it < NITER; ++it) {
        const float4* i4 = (it & 1) ? (const float4*)a4b : (const float4*)a4a;
        const float2* i2 = (it & 1) ? (const float2*)a2b : (const float2*)a2a;
        float4* o4 = (it & 1) ? a4a : a4b;
        float2* o2 = (it & 1) ? a2a : a2b;
        k_gru<<<9, 1024, 0, stream>>>(ws, i4, i2, o4, o2, y,
                                      hl + (it & 1)*64, hl + ((it + 1) & 1)*64);
    }
    k_out<<<1152, 256, 0, stream>>>(ws, owp, obp, (void*)d_out);
}

// Round 4
// 2599.247 us; speedup vs baseline: 8.2572x; 8.2572x over previous
//
#include <hip/hip_runtime.h>
#include <hip/hip_bf16.h>

#define PX 9216      // 96*96
#define LL 9216
#define HALF_L 4608
#define CCH 32       // emitted steps per chunk
#define NCHUNK 288   // 9216/32
#define WARM 128     // burn-in steps == pre-pad size
#define NITER 50
#define CB 4         // conv batch chunk
#define LLP 9344     // 9216 + 128 pre-pad per batch

// ws offsets (floats)
#define OFF_WC   0        // 32 scaled GRU consts
#define OFF_FLAG 32
#define OFF_HL   40       // 128
#define OFF_W1   192      // 144
#define OFF_B1   336      // 16
#define OFF_W2   384      // 4608
#define OFF_B2   4992     // 32
#define OFF_W3   5024     // 864
#define OFF_B3   5888     // 3
#define OFF_KX   5896     // 9
#define OFF_KY   5908     // 9
#define OFF_GRAY 8192     // 294912
#define OFF_G    303104   // 294912
#define OFF_MK   598016   // 294912
// padded gi buffers: (32*LLP + 128) positions
#define OFF_A4A  892928   // *4 floats = 1196544
#define OFF_A4B  2089472  // 1196544
#define OFF_A2A  3286016  // *2 floats = 598272
#define OFF_A2B  3884288  // 598272
#define OFF_Y    4482560  // 589824 ; end 5072384 floats = 20.3 MB
// conv scratch aliased over regions dead until GRU iter >= 1:
#define OFF_C1   OFF_A4B            // CB*16*9216 = 589824 <= 1196544
#define OFF_C2   OFF_A2B            // CB*32*9216 = 1179648 <= 598272+589824

static __device__ __forceinline__ float ldv(const void* p, long i, bool isb) {
    return isb ? __bfloat162float(((const __hip_bfloat16*)p)[i])
               : ((const float*)p)[i];
}

__global__ __launch_bounds__(256) void k_prep(
    float* __restrict__ ws, const void* img,
    const void* w1, const void* b1, const void* w2, const void* b2,
    const void* w3, const void* b3, const void* kx, const void* ky,
    const void* wih, const void* whh, const void* bih, const void* bhh)
{
    __shared__ float s_isb;
    int t = threadIdx.x;
    if (t == 0) {
        const unsigned short* u16 = (const unsigned short*)img;
        int cnt = 0;
        for (int k = 0; k < 256; ++k) {
            unsigned short u = u16[k];
            int e = (u >> 7) & 0xFF;
            bool ok = (u == 0) || (((u & 0x8000) == 0) && e >= 0x20 && e <= 0x7E);
            cnt += ok ? 1 : 0;
        }
        s_isb = (cnt >= 224) ? 1.f : 0.f;
        ws[OFF_FLAG] = s_isb;
    }
    __syncthreads();
    bool isb = s_isb > 0.5f;

    for (int i = t; i < 144; i += 256) { int co = i/9, tap = i%9; ws[OFF_W1 + tap*16 + co] = ldv(w1,i,isb); }
    for (int i = t; i < 16; i += 256) ws[OFF_B1+i] = ldv(b1,i,isb);
    for (int i = t; i < 4608; i += 256) { int co = i/144, r = i%144, ci = r/9, tap = r%9;
        ws[OFF_W2 + (ci*9+tap)*32 + co] = ldv(w2,i,isb); }
    for (int i = t; i < 32; i += 256) ws[OFF_B2+i] = ldv(b2,i,isb);
    for (int i = t; i < 864; i += 256) { int o = i/288, r = i%288, ci = r/9, tap = r%9;
        ws[OFF_W3 + (ci*9+tap)*3 + o] = ldv(w3,i,isb); }
    for (int i = t; i < 3; i += 256) ws[OFF_B3+i] = ldv(b3,i,isb);
    for (int i = t; i < 9; i += 256) { ws[OFF_KX+i] = ldv(kx,i,isb); ws[OFF_KY+i] = ldv(ky,i,isb); }
    for (int i = t; i < 128; i += 256) ws[OFF_HL+i] = 0.f;
    if (t == 0) {
        const float C1 = 1.4426950408889634f;
        for (int g = 0; g < 4; ++g) {   // r,z gates: scale by -log2e
            ws[OFF_WC + g*2+0]     = -C1*ldv(wih, g*2+0, isb);
            ws[OFF_WC + g*2+1]     = -C1*ldv(wih, g*2+1, isb);
            ws[OFF_WC + 8 + g*2+0] = -C1*ldv(whh, g*2+0, isb);
            ws[OFF_WC + 8 + g*2+1] = -C1*ldv(whh, g*2+1, isb);
            ws[OFF_WC + 16 + g]    = -C1*(ldv(bih,g,isb)+ldv(bhh,g,isb));
        }
        for (int j = 0; j < 2; ++j) {   // n gate: tanh(t)=1-2/(1+2^(2*log2e*t))
            int g = 4+j;
            ws[OFF_WC + 20 + j*2+0] = 2.f*C1*ldv(wih, g*2+0, isb);
            ws[OFF_WC + 20 + j*2+1] = 2.f*C1*ldv(wih, g*2+1, isb);
            ws[OFF_WC + 24 + j*2+0] = 2.f*C1*ldv(whh, g*2+0, isb);
            ws[OFF_WC + 24 + j*2+1] = 2.f*C1*ldv(whh, g*2+1, isb);
            ws[OFF_WC + 28 + j]     = 2.f*C1*ldv(bih, g, isb);
            ws[OFF_WC + 30 + j]     = 2.f*C1*ldv(bhh, g, isb);
        }
    }
}

__global__ __launch_bounds__(256) void k_gray(const void* __restrict__ img,
                                              float* __restrict__ ws)
{
    bool isb = ws[OFF_FLAG] > 0.5f;
    int t = blockIdx.x*256 + threadIdx.x;
    int b = t / PX, p = t - b*PX;
    long base = (long)b*3*PX;
    float r  = ldv(img, base + p, isb);
    float g  = ldv(img, base + PX + p, isb);
    float bl = ldv(img, base + 2*PX + p, isb);
    ws[OFF_GRAY + t] = fmaf(0.2989f, r, fmaf(0.587f, g, 0.114f*bl));
}

__global__ __launch_bounds__(256) void k_sobel(float* __restrict__ ws)
{
    int t = blockIdx.x*256 + threadIdx.x;
    int b = t / PX, p = t - b*PX;
    int y = p / 96, x = p - y*96;
    const float* g = ws + OFF_GRAY + b*PX;
    float gx = 0.f, gy = 0.f;
    #pragma unroll
    for (int dy = 0; dy < 3; ++dy)
    #pragma unroll
    for (int dx = 0; dx < 3; ++dx) {
        int yy = y+dy-1, xx = x+dx-1;
        float v = (yy >= 0 && yy < 96 && xx >= 0 && xx < 96) ? g[yy*96+xx] : 0.f;
        gx = fmaf(v, ws[OFF_KX + dy*3+dx], gx);
        gy = fmaf(v, ws[OFF_KY + dy*3+dx], gy);
    }
    ws[OFF_G + t] = sqrtf(fmaf(gx, gx, gy*gy));
}

__global__ __launch_bounds__(256) void k_conv1(float* __restrict__ ws, int b0)
{
    int t = blockIdx.x*256 + threadIdx.x;   // CB*9216 threads
    int bb = t / PX, p = t - bb*PX;
    int y = p / 96, x = p - y*96;
    const float* g = ws + OFF_GRAY + (b0+bb)*PX;
    float acc[16];
    #pragma unroll
    for (int co = 0; co < 16; ++co) acc[co] = 0.f;
    #pragma unroll
    for (int dy = 0; dy < 3; ++dy)
    #pragma unroll
    for (int dx = 0; dx < 3; ++dx) {
        int yy = y+dy-1, xx = x+dx-1;
        float v = (yy >= 0 && yy < 96 && xx >= 0 && xx < 96) ? g[yy*96+xx] : 0.f;
        const float* w = ws + OFF_W1 + (dy*3+dx)*16;
        #pragma unroll
        for (int co = 0; co < 16; ++co) acc[co] = fmaf(v, w[co], acc[co]);
    }
    float* o = ws + OFF_C1 + bb*16*PX + p;
    #pragma unroll
    for (int co = 0; co < 16; ++co)
        o[co*PX] = fmaxf(acc[co] + ws[OFF_B1+co], 0.f);
}

__global__ __launch_bounds__(256) void k_conv2(float* __restrict__ ws)
{
    __shared__ float tile[16*324];   // 16 ci x 18x18 halo
    int bb = blockIdx.x / 36;
    int tI = blockIdx.x % 36;
    int ty0 = (tI / 6) * 16, tx0 = (tI % 6) * 16;
    int t = threadIdx.x;
    for (int i = t; i < 5184; i += 256) {
        int ci = i / 324, r = i - ci*324;
        int yy = r / 18, xx = r - yy*18;
        int gy = ty0 + yy - 1, gx = tx0 + xx - 1;
        float v = 0.f;
        if (gy >= 0 && gy < 96 && gx >= 0 && gx < 96)
            v = ws[OFF_C1 + (bb*16 + ci)*PX + gy*96 + gx];
        tile[i] = v;
    }
    __syncthreads();
    int ty = t / 16, tx = t - (t/16)*16;
    float acc[32];
    #pragma unroll
    for (int co = 0; co < 32; ++co) acc[co] = 0.f;
    for (int ci = 0; ci < 16; ++ci) {
        #pragma unroll
        for (int dy = 0; dy < 3; ++dy)
        #pragma unroll
        for (int dx = 0; dx < 3; ++dx) {
            float v = tile[ci*324 + (ty+dy)*18 + (tx+dx)];
            const float* w = ws + OFF_W2 + (ci*9 + dy*3 + dx)*32;
            #pragma unroll
            for (int co = 0; co < 32; ++co) acc[co] = fmaf(v, w[co], acc[co]);
        }
    }
    int p = (ty0+ty)*96 + tx0 + tx;
    float* o = ws + OFF_C2 + bb*32*PX + p;
    #pragma unroll
    for (int co = 0; co < 32; ++co)
        o[co*PX] = fmaxf(acc[co] + ws[OFF_B2+co], 0.f);
}

__global__ __launch_bounds__(256) void k_conv3(float* __restrict__ ws, int b0)
{
    int t = blockIdx.x*256 + threadIdx.x;
    int bb = t / PX, p = t - bb*PX;
    int y = p / 96, x = p - y*96;
    float a0 = 0.f, a1 = 0.f, a2 = 0.f;
    for (int ci = 0; ci < 32; ++ci) {
        const float* s = ws + OFF_C2 + (bb*32 + ci)*PX;
        #pragma unroll
        for (int dy = 0; dy < 3; ++dy)
        #pragma unroll
        for (int dx = 0; dx < 3; ++dx) {
            int yy = y+dy-1, xx = x+dx-1;
            float v = (yy >= 0 && yy < 96 && xx >= 0 && xx < 96) ? s[yy*96+xx] : 0.f;
            const float* w = ws + OFF_W3 + (ci*9 + dy*3 + dx)*3;
            a0 = fmaf(v, w[0], a0);
            a1 = fmaf(v, w[1], a1);
            a2 = fmaf(v, w[2], a2);
        }
    }
    a0 += ws[OFF_B3+0]; a1 += ws[OFF_B3+1]; a2 += ws[OFF_B3+2];
    int m = 0; float best = a0;
    if (a1 > best) { best = a1; m = 1; }
    if (a2 > best) { m = 2; }
    ws[OFF_MK + (b0+bb)*PX + p] = (float)m;
}

// pack x=(v0,v1) per position and seed gi buffers (padded layout) for iter 0
__global__ __launch_bounds__(256) void k_pack(float* __restrict__ ws)
{
    int t = blockIdx.x*256 + threadIdx.x;   // 0..294911
    int b = t / LL, l = t - b*LL;
    float v0, v1;
    if (l < HALF_L) {
        const float* m = ws + OFF_MK + b*PX + 2*l;
        v0 = m[0]; v1 = m[1];
    } else {
        const float* g = ws + OFF_G + b*PX + 2*(l - HALF_L);
        v0 = g[0]; v1 = g[1];
    }
    const float* kk = ws + OFF_WC;
    float4 g4;
    g4.x = fmaf(kk[0], v0, fmaf(kk[1], v1, kk[16]));
    g4.y = fmaf(kk[2], v0, fmaf(kk[3], v1, kk[17]));
    g4.z = fmaf(kk[4], v0, fmaf(kk[5], v1, kk[18]));
    g4.w = fmaf(kk[6], v0, fmaf(kk[7], v1, kk[19]));
    float2 g2;
    g2.x = fmaf(kk[20], v0, fmaf(kk[21], v1, kk[28]));
    g2.y = fmaf(kk[22], v0, fmaf(kk[23], v1, kk[29]));
    long idx = (long)b*LLP + WARM + l;
    ((float4*)(ws + OFF_A4A))[idx] = g4;
    ((float2*)(ws + OFF_A2A))[idx] = g2;
}

__global__ __launch_bounds__(256) void k_gru(const float* __restrict__ ws,
                                             const float4* __restrict__ g4in,
                                             const float2* __restrict__ g2in,
                                             float4* __restrict__ g4out,
                                             float2* __restrict__ g2out,
                                             float2* __restrict__ yout,
                                             const float* __restrict__ hlin,
                                             float* __restrict__ hlout)
{
    int i = blockIdx.x*256 + threadIdx.x;   // 9216 threads exactly
    int b = i / NCHUNK, c = i - b*NCHUNK;
    float kk[32];
    #pragma unroll
    for (int j = 0; j < 32; ++j) kk[j] = ws[OFF_WC + j];

    int emit  = c * CCH;
    int jstar = WARM - emit;          // j where l==0: exact-h reset (never fires if <0)
    float hl0 = hlin[2*b], hl1 = hlin[2*b+1];
    float h0 = 0.f, h1 = 0.f;

    long base = (long)b*LLP + emit;   // == (b*LLP + WARM) + (emit - WARM)
    const float4* s4 = g4in + base;
    const float2* s2 = g2in + base;
    float4*       d4 = g4out + base;
    float2*       d2 = g2out + base;
    float2*       dy = yout + (long)b*LL + (emit - WARM);

    auto STEP = [&](const float4& g4, float gn0, float gn1) {
        float ar0 = fmaf(kk[8],  h0, fmaf(kk[9],  h1, g4.x));
        float ar1 = fmaf(kk[10], h0, fmaf(kk[11], h1, g4.y));
        float az0 = fmaf(kk[12], h0, fmaf(kk[13], h1, g4.z));
        float az1 = fmaf(kk[14], h0, fmaf(kk[15], h1, g4.w));
        float er0 = __builtin_amdgcn_exp2f(fminf(ar0, 60.f));
        float er1 = __builtin_amdgcn_exp2f(fminf(ar1, 60.f));
        float ez0 = __builtin_amdgcn_exp2f(fminf(az0, 60.f));
        float ez1 = __builtin_amdgcn_exp2f(fminf(az1, 60.f));
        float tr0 = 1.f + er0, tr1 = 1.f + er1;
        float tz0 = 1.f + ez0, tz1 = 1.f + ez1;
        float iR = __builtin_amdgcn_rcpf(tr0*tr1);
        float iZ = __builtin_amdgcn_rcpf(tz0*tz1);
        float r0 = iR*tr1, r1 = iR*tr0;
        float z0 = iZ*tz1, z1 = iZ*tz0;
        float hn0 = fmaf(kk[24], h0, fmaf(kk[25], h1, kk[30]));
        float hn1 = fmaf(kk[26], h0, fmaf(kk[27], h1, kk[31]));
        float u0 = fmaf(r0, hn0, gn0);
        float u1 = fmaf(r1, hn1, gn1);
        float e0 = __builtin_amdgcn_exp2f(fminf(u0, 60.f));
        float e1 = __builtin_amdgcn_exp2f(fminf(u1, 60.f));
        float s0 = 1.f + e0, s1 = 1.f + e1;
        float iN = __builtin_amdgcn_rcpf(s0*s1);
        float m2 = -2.f*iN;
        float n0 = fmaf(m2, s1, 1.f);
        float n1 = fmaf(m2, s0, 1.f);
        h0 = fmaf(z0, h0 - n0, n0);
        h1 = fmaf(z1, h1 - n1, n1);
    };

    auto GI4 = [&](float y0, float y1) {
        return make_float4(fmaf(kk[0], y0, fmaf(kk[1], y1, kk[16])),
                           fmaf(kk[2], y0, fmaf(kk[3], y1, kk[17])),
                           fmaf(kk[4], y0, fmaf(kk[5], y1, kk[18])),
                           fmaf(kk[6], y0, fmaf(kk[7], y1, kk[19])));
    };

    float4 c40 = s4[0], c41 = s4[1], c42 = s4[2], c43 = s4[3];
    float4 c2a = *(const float4*)(s2 + 0);
    float4 c2b = *(const float4*)(s2 + 2);

    // wave-uniform trip count: all lanes run exactly WARM+CCH steps
    for (int j = 0; j < WARM + CCH; j += 4) {
        float4 n40 = s4[j+4], n41 = s4[j+5], n42 = s4[j+6], n43 = s4[j+7];
        float4 n2a = *(const float4*)(s2 + j + 4);
        float4 n2b = *(const float4*)(s2 + j + 6);
        if (j == jstar) { h0 = hl0; h1 = hl1; }   // exact carry at l==0 (trip-aligned)
        STEP(c40, c2a.x, c2a.y); float y00 = fmaxf(h0,0.f), y01 = fmaxf(h1,0.f);
        STEP(c41, c2a.z, c2a.w); float y10 = fmaxf(h0,0.f), y11 = fmaxf(h1,0.f);
        STEP(c42, c2b.x, c2b.y); float y20 = fmaxf(h0,0.f), y21 = fmaxf(h1,0.f);
        STEP(c43, c2b.z, c2b.w); float y30 = fmaxf(h0,0.f), y31 = fmaxf(h1,0.f);
        if (j >= WARM) {                           // wave-uniform emit condition
            d4[j]   = GI4(y00, y01);
            d4[j+1] = GI4(y10, y11);
            d4[j+2] = GI4(y20, y21);
            d4[j+3] = GI4(y30, y31);
            *(float4*)(d2 + j)     = make_float4(
                fmaf(kk[20],y00, fmaf(kk[21],y01, kk[28])),
                fmaf(kk[22],y00, fmaf(kk[23],y01, kk[29])),
                fmaf(kk[20],y10, fmaf(kk[21],y11, kk[28])),
                fmaf(kk[22],y10, fmaf(kk[23],y11, kk[29])));
            *(float4*)(d2 + j + 2) = make_float4(
                fmaf(kk[20],y20, fmaf(kk[21],y21, kk[28])),
                fmaf(kk[22],y20, fmaf(kk[23],y21, kk[29])),
                fmaf(kk[20],y30, fmaf(kk[21],y31, kk[28])),
                fmaf(kk[22],y30, fmaf(kk[23],y31, kk[29])));
            *(float4*)(dy + j)     = make_float4(y00, y01, y10, y11);
            *(float4*)(dy + j + 2) = make_float4(y20, y21, y30, y31);
        }
        c40 = n40; c41 = n41; c42 = n42; c43 = n43;
        c2a = n2a; c2b = n2b;
    }
    if (c == NCHUNK-1) { hlout[2*b] = h0; hlout[2*b+1] = h1; }
}

__global__ __launch_bounds__(256) void k_out(const float* __restrict__ ws,
                                             const void* __restrict__ ow,
                                             const void* __restrict__ ob,
                                             void* __restrict__ out)
{
    bool isb = ws[OFF_FLAG] > 0.5f;
    int t = blockIdx.x*256 + threadIdx.x;
    int b = t / PX, p = t - b*PX;
    float2 v = ((const float2*)(ws + OFF_Y))[b*LL + p];
    #pragma unroll
    for (int o = 0; o < 3; ++o) {
        float w0 = ldv(ow, o*2,   isb);
        float w1 = ldv(ow, o*2+1, isb);
        float bi = ldv(ob, o,     isb);
        float r = fmaf(v.y, w1, fmaf(v.x, w0, bi));
        long idx = (long)(b*3 + o)*PX + p;
        if (isb) ((__hip_bfloat16*)out)[idx] = __float2bfloat16(r);
        else     ((float*)out)[idx] = r;
    }
}

extern "C" void kernel_launch(void* const* d_in, const int* in_sizes, int n_in,
                              void* d_out, int out_size, void* d_ws, size_t ws_size,
                              hipStream_t stream)
{
    (void)in_sizes; (void)n_in; (void)out_size; (void)ws_size;
    float* ws = (float*)d_ws;
    const void* img = d_in[0];
    const void* kx  = d_in[1];
    const void* ky  = d_in[2];
    const void* w1  = d_in[3];
    const void* b1  = d_in[4];
    const void* w2  = d_in[5];
    const void* b2  = d_in[6];
    const void* w3  = d_in[7];
    const void* b3  = d_in[8];
    const void* wih = d_in[9];
    const void* whh = d_in[10];
    const void* bih = d_in[11];
    const void* bhh = d_in[12];
    const void* owp = d_in[13];
    const void* obp = d_in[14];

    k_prep<<<1, 256, 0, stream>>>(ws, img, w1,b1,w2,b2,w3,b3,kx,ky,wih,whh,bih,bhh);
    k_gray<<<1152, 256, 0, stream>>>(img, ws);
    k_sobel<<<1152, 256, 0, stream>>>(ws);
    for (int q = 0; q < 8; ++q) {          // batch chunks of CB=4
        k_conv1<<<144, 256, 0, stream>>>(ws, q*CB);
        k_conv2<<<144, 256, 0, stream>>>(ws);
        k_conv3<<<144, 256, 0, stream>>>(ws, q*CB);
    }
    k_pack<<<1152, 256, 0, stream>>>(ws);

    float4* a4a = (float4*)(ws + OFF_A4A);
    float4* a4b = (float4*)(ws + OFF_A4B);
    float2* a2a = (float2*)(ws + OFF_A2A);
    float2* a2b = (float2*)(ws + OFF_A2B);
    float2* y   = (float2*)(ws + OFF_Y);
    float* hl = ws + OFF_HL;
    for (int it = 0; it < NITER; ++it) {
        const float4* i4 = (it & 1) ? (const float4*)a4b : (const float4*)a4a;
        const float2* i2 = (it & 1) ? (const float2*)a2b : (const float2*)a2a;
        float4* o4 = (it & 1) ? a4a : a4b;
        float2* o2 = (it & 1) ? a2a : a2b;
        k_gru<<<36, 256, 0, stream>>>(ws, i4, i2, o4, o2, y,
                                      hl + (it & 1)*64, hl + ((it + 1) & 1)*64);
    }
    k_out<<<1152, 256, 0, stream>>>(ws, owp, obp, (void*)d_out);
}

// Round 5
// 1569.092 us; speedup vs baseline: 13.6783x; 1.6565x over previous
//
#include <hip/hip_runtime.h>
#include <hip/hip_bf16.h>

#define PX 9216      // 96*96
#define LL 9216
#define HALF_L 4608
#define CCH 16       // emitted steps per chunk
#define NCHUNK 576   // 9216/16
#define WARM 128     // burn-in steps (8 chunks of pre-pad)
#define PADC 8       // WARM/CCH
#define NCP  584     // NCHUNK + PADC
#define RS   18688   // 32*NCP (float2 row stride for s)
#define NITER 50
#define CB 4         // conv batch chunk

// ws offsets (floats)
#define OFF_WC   0        // 32 scaled GRU consts
#define OFF_FLAG 32
#define OFF_HL   40       // 128
#define OFF_W1   192      // 144
#define OFF_B1   336      // 16
#define OFF_W2   384      // 4608
#define OFF_B2   4992     // 32
#define OFF_W3   5024     // 864
#define OFF_B3   5888     // 3
#define OFF_KX   5896     // 9
#define OFF_KY   5904     // 9 (moved; 8-aligned)
#define OFF_GRAY 8192     // 294912
#define OFF_G    303104   // 294912
#define OFF_MK   598016   // 294912
// transposed y buffers: 16*32*NCP float2 = 598016 floats (+64 pad)
#define OFF_C2   892928   // 1179648 floats, ends 2072576
#define OFF_YA   892928   // 598144 <= C2 region (pack writes after convs done)
#define OFF_YB   2072640  // 598144; ends 2670784
#define OFF_C1   2072640  // 589824 <= YB region (YB dead until GRU iter 0)
// total ws: 2670784 floats = 10.7 MB

static __device__ __forceinline__ float ldv(const void* p, long i, bool isb) {
    return isb ? __bfloat162float(((const __hip_bfloat16*)p)[i])
               : ((const float*)p)[i];
}

__global__ __launch_bounds__(256) void k_prep(
    float* __restrict__ ws, const void* img,
    const void* w1, const void* b1, const void* w2, const void* b2,
    const void* w3, const void* b3, const void* kx, const void* ky,
    const void* wih, const void* whh, const void* bih, const void* bhh)
{
    __shared__ float s_isb;
    int t = threadIdx.x;
    if (t == 0) {
        const unsigned short* u16 = (const unsigned short*)img;
        int cnt = 0;
        for (int k = 0; k < 256; ++k) {
            unsigned short u = u16[k];
            int e = (u >> 7) & 0xFF;
            bool ok = (u == 0) || (((u & 0x8000) == 0) && e >= 0x20 && e <= 0x7E);
            cnt += ok ? 1 : 0;
        }
        s_isb = (cnt >= 224) ? 1.f : 0.f;
        ws[OFF_FLAG] = s_isb;
    }
    __syncthreads();
    bool isb = s_isb > 0.5f;

    for (int i = t; i < 144; i += 256) { int co = i/9, tap = i%9; ws[OFF_W1 + tap*16 + co] = ldv(w1,i,isb); }
    for (int i = t; i < 16; i += 256) ws[OFF_B1+i] = ldv(b1,i,isb);
    for (int i = t; i < 4608; i += 256) { int co = i/144, r = i%144, ci = r/9, tap = r%9;
        ws[OFF_W2 + (ci*9+tap)*32 + co] = ldv(w2,i,isb); }
    for (int i = t; i < 32; i += 256) ws[OFF_B2+i] = ldv(b2,i,isb);
    for (int i = t; i < 864; i += 256) { int o = i/288, r = i%288, ci = r/9, tap = r%9;
        ws[OFF_W3 + (ci*9+tap)*3 + o] = ldv(w3,i,isb); }
    for (int i = t; i < 3; i += 256) ws[OFF_B3+i] = ldv(b3,i,isb);
    for (int i = t; i < 9; i += 256) { ws[OFF_KX+i] = ldv(kx,i,isb); ws[OFF_KY+i] = ldv(ky,i,isb); }
    for (int i = t; i < 128; i += 256) ws[OFF_HL+i] = 0.f;
    if (t == 0) {
        const float C1 = 1.4426950408889634f;
        for (int g = 0; g < 4; ++g) {   // r,z gates: scale by -log2e (sigmoid = rcp(1+exp2(arg)))
            ws[OFF_WC + g*2+0]     = -C1*ldv(wih, g*2+0, isb);
            ws[OFF_WC + g*2+1]     = -C1*ldv(wih, g*2+1, isb);
            ws[OFF_WC + 8 + g*2+0] = -C1*ldv(whh, g*2+0, isb);
            ws[OFF_WC + 8 + g*2+1] = -C1*ldv(whh, g*2+1, isb);
            ws[OFF_WC + 16 + g]    = -C1*(ldv(bih,g,isb)+ldv(bhh,g,isb));
        }
        for (int j = 0; j < 2; ++j) {   // n gate: tanh(t)=1-2/(1+2^(2t*log2e))
            int g = 4+j;
            ws[OFF_WC + 20 + j*2+0] = 2.f*C1*ldv(wih, g*2+0, isb);
            ws[OFF_WC + 20 + j*2+1] = 2.f*C1*ldv(wih, g*2+1, isb);
            ws[OFF_WC + 24 + j*2+0] = 2.f*C1*ldv(whh, g*2+0, isb);
            ws[OFF_WC + 24 + j*2+1] = 2.f*C1*ldv(whh, g*2+1, isb);
            ws[OFF_WC + 28 + j]     = 2.f*C1*ldv(bih, g, isb);
            ws[OFF_WC + 30 + j]     = 2.f*C1*ldv(bhh, g, isb);
        }
    }
}

__global__ __launch_bounds__(256) void k_gray(const void* __restrict__ img,
                                              float* __restrict__ ws)
{
    bool isb = ws[OFF_FLAG] > 0.5f;
    int t = blockIdx.x*256 + threadIdx.x;
    int b = t / PX, p = t - b*PX;
    long base = (long)b*3*PX;
    float r  = ldv(img, base + p, isb);
    float g  = ldv(img, base + PX + p, isb);
    float bl = ldv(img, base + 2*PX + p, isb);
    ws[OFF_GRAY + t] = fmaf(0.2989f, r, fmaf(0.587f, g, 0.114f*bl));
}

__global__ __launch_bounds__(256) void k_sobel(float* __restrict__ ws)
{
    int t = blockIdx.x*256 + threadIdx.x;
    int b = t / PX, p = t - b*PX;
    int y = p / 96, x = p - y*96;
    const float* g = ws + OFF_GRAY + b*PX;
    float gx = 0.f, gy = 0.f;
    #pragma unroll
    for (int dy = 0; dy < 3; ++dy)
    #pragma unroll
    for (int dx = 0; dx < 3; ++dx) {
        int yy = y+dy-1, xx = x+dx-1;
        float v = (yy >= 0 && yy < 96 && xx >= 0 && xx < 96) ? g[yy*96+xx] : 0.f;
        gx = fmaf(v, ws[OFF_KX + dy*3+dx], gx);
        gy = fmaf(v, ws[OFF_KY + dy*3+dx], gy);
    }
    ws[OFF_G + t] = sqrtf(fmaf(gx, gx, gy*gy));
}

__global__ __launch_bounds__(256) void k_conv1(float* __restrict__ ws, int b0)
{
    int t = blockIdx.x*256 + threadIdx.x;   // CB*9216 threads
    int bb = t / PX, p = t - bb*PX;
    int y = p / 96, x = p - y*96;
    const float* g = ws + OFF_GRAY + (b0+bb)*PX;
    float acc[16];
    #pragma unroll
    for (int co = 0; co < 16; ++co) acc[co] = 0.f;
    #pragma unroll
    for (int dy = 0; dy < 3; ++dy)
    #pragma unroll
    for (int dx = 0; dx < 3; ++dx) {
        int yy = y+dy-1, xx = x+dx-1;
        float v = (yy >= 0 && yy < 96 && xx >= 0 && xx < 96) ? g[yy*96+xx] : 0.f;
        const float* w = ws + OFF_W1 + (dy*3+dx)*16;
        #pragma unroll
        for (int co = 0; co < 16; ++co) acc[co] = fmaf(v, w[co], acc[co]);
    }
    float* o = ws + OFF_C1 + bb*16*PX + p;
    #pragma unroll
    for (int co = 0; co < 16; ++co)
        o[co*PX] = fmaxf(acc[co] + ws[OFF_B1+co], 0.f);
}

__global__ __launch_bounds__(256) void k_conv2(float* __restrict__ ws)
{
    __shared__ float tile[16*324];   // 16 ci x 18x18 halo
    int bb = blockIdx.x / 36;
    int tI = blockIdx.x % 36;
    int ty0 = (tI / 6) * 16, tx0 = (tI % 6) * 16;
    int t = threadIdx.x;
    for (int i = t; i < 5184; i += 256) {
        int ci = i / 324, r = i - ci*324;
        int yy = r / 18, xx = r - yy*18;
        int gy = ty0 + yy - 1, gx = tx0 + xx - 1;
        float v = 0.f;
        if (gy >= 0 && gy < 96 && gx >= 0 && gx < 96)
            v = ws[OFF_C1 + (bb*16 + ci)*PX + gy*96 + gx];
        tile[i] = v;
    }
    __syncthreads();
    int ty = t / 16, tx = t - (t/16)*16;
    float acc[32];
    #pragma unroll
    for (int co = 0; co < 32; ++co) acc[co] = 0.f;
    for (int ci = 0; ci < 16; ++ci) {
        #pragma unroll
        for (int dy = 0; dy < 3; ++dy)
        #pragma unroll
        for (int dx = 0; dx < 3; ++dx) {
            float v = tile[ci*324 + (ty+dy)*18 + (tx+dx)];
            const float* w = ws + OFF_W2 + (ci*9 + dy*3 + dx)*32;
            #pragma unroll
            for (int co = 0; co < 32; ++co) acc[co] = fmaf(v, w[co], acc[co]);
        }
    }
    int p = (ty0+ty)*96 + tx0 + tx;
    float* o = ws + OFF_C2 + bb*32*PX + p;
    #pragma unroll
    for (int co = 0; co < 32; ++co)
        o[co*PX] = fmaxf(acc[co] + ws[OFF_B2+co], 0.f);
}

__global__ __launch_bounds__(256) void k_conv3(float* __restrict__ ws, int b0)
{
    int t = blockIdx.x*256 + threadIdx.x;
    int bb = t / PX, p = t - bb*PX;
    int y = p / 96, x = p - y*96;
    float a0 = 0.f, a1 = 0.f, a2 = 0.f;
    for (int ci = 0; ci < 32; ++ci) {
        const float* s = ws + OFF_C2 + (bb*32 + ci)*PX;
        #pragma unroll
        for (int dy = 0; dy < 3; ++dy)
        #pragma unroll
        for (int dx = 0; dx < 3; ++dx) {
            int yy = y+dy-1, xx = x+dx-1;
            float v = (yy >= 0 && yy < 96 && xx >= 0 && xx < 96) ? s[yy*96+xx] : 0.f;
            const float* w = ws + OFF_W3 + (ci*9 + dy*3 + dx)*3;
            a0 = fmaf(v, w[0], a0);
            a1 = fmaf(v, w[1], a1);
            a2 = fmaf(v, w[2], a2);
        }
    }
    a0 += ws[OFF_B3+0]; a1 += ws[OFF_B3+1]; a2 += ws[OFF_B3+2];
    int m = 0; float best = a0;
    if (a1 > best) { best = a1; m = 1; }
    if (a2 > best) { m = 2; }
    ws[OFF_MK + (b0+bb)*PX + p] = (float)m;
}

// pack x=(v0,v1) into transposed layout y[s][b][cp]
__global__ __launch_bounds__(256) void k_pack(float* __restrict__ ws)
{
    int t = blockIdx.x*256 + threadIdx.x;   // 0..294911
    int b = t / LL, l = t - b*LL;
    float v0, v1;
    if (l < HALF_L) {
        const float* m = ws + OFF_MK + b*PX + 2*l;
        v0 = m[0]; v1 = m[1];
    } else {
        const float* g = ws + OFF_G + b*PX + 2*(l - HALF_L);
        v0 = g[0]; v1 = g[1];
    }
    int c = l >> 4, s = l & 15;
    long idx = (long)(s*32 + b)*NCP + c + PADC;
    ((float2*)(ws + OFF_YA))[idx] = make_float2(v0, v1);
}

__global__ __launch_bounds__(256) void k_gru(const float* __restrict__ ws,
                                             const float2* __restrict__ S,
                                             float2* __restrict__ D,
                                             const float* __restrict__ hlin,
                                             float* __restrict__ hlout)
{
    int i = blockIdx.x*256 + threadIdx.x;   // 18432 threads exactly
    int b = i / NCHUNK, c = i - b*NCHUNK;
    float kk[32];
    #pragma unroll
    for (int j = 0; j < 32; ++j) kk[j] = ws[OFF_WC + j];

    int jstar = WARM - c*CCH;               // trip-aligned exact-carry reset point
    float hl0 = hlin[2*b], hl1 = hlin[2*b+1];
    float h0 = 0.f, h1 = 0.f;
    long B0 = (long)b*NCP + c;              // float2 index base

    auto STEP = [&](float v0, float v1) {
        // gate inputs from loaded y — independent of h, off the serial chain
        float gr0 = fmaf(kk[0], v0, fmaf(kk[1], v1, kk[16]));
        float gr1 = fmaf(kk[2], v0, fmaf(kk[3], v1, kk[17]));
        float gz0 = fmaf(kk[4], v0, fmaf(kk[5], v1, kk[18]));
        float gz1 = fmaf(kk[6], v0, fmaf(kk[7], v1, kk[19]));
        float gn0 = fmaf(kk[20], v0, fmaf(kk[21], v1, kk[28]));
        float gn1 = fmaf(kk[22], v0, fmaf(kk[23], v1, kk[29]));
        float ar0 = fmaf(kk[8],  h0, fmaf(kk[9],  h1, gr0));
        float ar1 = fmaf(kk[10], h0, fmaf(kk[11], h1, gr1));
        float az0 = fmaf(kk[12], h0, fmaf(kk[13], h1, gz0));
        float az1 = fmaf(kk[14], h0, fmaf(kk[15], h1, gz1));
        float r0 = __builtin_amdgcn_rcpf(1.f + __builtin_amdgcn_exp2f(ar0));
        float r1 = __builtin_amdgcn_rcpf(1.f + __builtin_amdgcn_exp2f(ar1));
        float z0 = __builtin_amdgcn_rcpf(1.f + __builtin_amdgcn_exp2f(az0));
        float z1 = __builtin_amdgcn_rcpf(1.f + __builtin_amdgcn_exp2f(az1));
        float hn0 = fmaf(kk[24], h0, fmaf(kk[25], h1, kk[30]));
        float hn1 = fmaf(kk[26], h0, fmaf(kk[27], h1, kk[31]));
        float u0 = fmaf(r0, hn0, gn0);
        float u1 = fmaf(r1, hn1, gn1);
        float iN0 = __builtin_amdgcn_rcpf(1.f + __builtin_amdgcn_exp2f(u0));
        float iN1 = __builtin_amdgcn_rcpf(1.f + __builtin_amdgcn_exp2f(u1));
        float n0 = fmaf(-2.f, iN0, 1.f);
        float n1 = fmaf(-2.f, iN1, 1.f);
        float omz0 = 1.f - z0, zh0 = z0*h0;   // parallel z-path, ready before n
        float omz1 = 1.f - z1, zh1 = z1*h1;
        h0 = fmaf(n0, omz0, zh0);
        h1 = fmaf(n1, omz1, zh1);
    };

    // preload trip 0 (g=0, s=0..3)
    float2 y0 = S[B0 + 0*RS];
    float2 y1 = S[B0 + 1*RS];
    float2 y2 = S[B0 + 2*RS];
    float2 y3 = S[B0 + 3*RS];

    for (int T = 0; T < 36; ++T) {          // 36 trips x 4 steps = 144 steps
        int Tn = T + 1;
        long bn = B0 + (Tn >> 2);           // next trip's group offset
        int sn = (Tn & 3) << 2;
        float2 p0 = S[bn + (sn+0)*(long)RS];
        float2 p1 = S[bn + (sn+1)*(long)RS];
        float2 p2 = S[bn + (sn+2)*(long)RS];
        float2 p3 = S[bn + (sn+3)*(long)RS];
        if (T*4 == jstar) { h0 = hl0; h1 = hl1; }  // exact carry at global l==0
        STEP(y0.x, y0.y); float e00 = fmaxf(h0,0.f), e01 = fmaxf(h1,0.f);
        STEP(y1.x, y1.y); float e10 = fmaxf(h0,0.f), e11 = fmaxf(h1,0.f);
        STEP(y2.x, y2.y); float e20 = fmaxf(h0,0.f), e21 = fmaxf(h1,0.f);
        STEP(y3.x, y3.y); float e30 = fmaxf(h0,0.f), e31 = fmaxf(h1,0.f);
        if (T >= 32) {                      // emit group g==8, wave-uniform
            int s0 = (T & 3) << 2;
            long db = B0 + PADC;
            D[db + (s0+0)*(long)RS] = make_float2(e00, e01);
            D[db + (s0+1)*(long)RS] = make_float2(e10, e11);
            D[db + (s0+2)*(long)RS] = make_float2(e20, e21);
            D[db + (s0+3)*(long)RS] = make_float2(e30, e31);
        }
        y0 = p0; y1 = p1; y2 = p2; y3 = p3;
    }
    if (c == NCHUNK-1) { hlout[2*b] = h0; hlout[2*b+1] = h1; }
}

__global__ __launch_bounds__(256) void k_out(const float* __restrict__ ws,
                                             const void* __restrict__ ow,
                                             const void* __restrict__ ob,
                                             void* __restrict__ out)
{
    bool isb = ws[OFF_FLAG] > 0.5f;
    int t = blockIdx.x*256 + threadIdx.x;
    int b = t / PX, p = t - b*PX;
    int c = p >> 4, s = p & 15;
    float2 v = ((const float2*)(ws + OFF_YA))[(long)(s*32 + b)*NCP + c + PADC];
    #pragma unroll
    for (int o = 0; o < 3; ++o) {
        float w0 = ldv(ow, o*2,   isb);
        float w1 = ldv(ow, o*2+1, isb);
        float bi = ldv(ob, o,     isb);
        float r = fmaf(v.y, w1, fmaf(v.x, w0, bi));
        long idx = (long)(b*3 + o)*PX + p;
        if (isb) ((__hip_bfloat16*)out)[idx] = __float2bfloat16(r);
        else     ((float*)out)[idx] = r;
    }
}

extern "C" void kernel_launch(void* const* d_in, const int* in_sizes, int n_in,
                              void* d_out, int out_size, void* d_ws, size_t ws_size,
                              hipStream_t stream)
{
    (void)in_sizes; (void)n_in; (void)out_size; (void)ws_size;
    float* ws = (float*)d_ws;
    const void* img = d_in[0];
    const void* kx  = d_in[1];
    const void* ky  = d_in[2];
    const void* w1  = d_in[3];
    const void* b1  = d_in[4];
    const void* w2  = d_in[5];
    const void* b2  = d_in[6];
    const void* w3  = d_in[7];
    const void* b3  = d_in[8];
    const void* wih = d_in[9];
    const void* whh = d_in[10];
    const void* bih = d_in[11];
    const void* bhh = d_in[12];
    const void* owp = d_in[13];
    const void* obp = d_in[14];

    k_prep<<<1, 256, 0, stream>>>(ws, img, w1,b1,w2,b2,w3,b3,kx,ky,wih,whh,bih,bhh);
    k_gray<<<1152, 256, 0, stream>>>(img, ws);
    k_sobel<<<1152, 256, 0, stream>>>(ws);
    for (int q = 0; q < 8; ++q) {          // batch chunks of CB=4
        k_conv1<<<144, 256, 0, stream>>>(ws, q*CB);
        k_conv2<<<144, 256, 0, stream>>>(ws);
        k_conv3<<<144, 256, 0, stream>>>(ws, q*CB);
    }
    k_pack<<<1152, 256, 0, stream>>>(ws);

    float2* ya = (float2*)(ws + OFF_YA);
    float2* yb = (float2*)(ws + OFF_YB);
    float* hl = ws + OFF_HL;
    for (int it = 0; it < NITER; ++it) {
        const float2* src = (it & 1) ? (const float2*)yb : (const float2*)ya;
        float2* dst = (it & 1) ? ya : yb;
        k_gru<<<72, 256, 0, stream>>>(ws, src, dst,
                                      hl + (it & 1)*64, hl + ((it + 1) & 1)*64);
    }
    k_out<<<1152, 256, 0, stream>>>(ws, owp, obp, (void*)d_out);
}